// Round 17
// baseline (544.059 us; speedup 1.0000x reference)
//
#include <hip/hip_runtime.h>

// SpatialEvoProp — R20: R17 revert + work-stealing groups + scanB fusion.
// R19 lesson: sP-from-global regressed (featQ stream thrashes 32KB L1 ->
// P reads become L2 round-trips; HW never packed 8 blocks/CU: occ stayed
// 50%). Wave-count lever EXHAUSTED; R17 (sPh in LDS f16, 6 blocks/CU) is
// the proven best (k_edge 84.5, total 255.9). This round: (1) fix k_edge's
// tail — 25000 groups / 6144 waves = 4.07 avg but 424 waves carry 5 ->
// makespan 5/4.07 = ~20% tail. Run-merging is intra-group, so assignment
// can be dynamic: work-steal pop via one atomicAdd per wave-iter (gctr in
// ws, zeroed by k_prep each replay). (2) fuse k_scanB into k_scanC (each
// block prefixes the 49 partials from LDS) — one fewer launch.
// Poisoned: 512-thr blocks (R4), lb(256,8) VGPR cap (R18), sP-from-global
// (R19 L1 thrash), cross-iter state dup (R5/R10), split tables (R6),
// row-byte shrink (R7/R8), source batching for VGPR (R12).

#define DFEAT 64

typedef __attribute__((ext_vector_type(8))) _Float16 half8;
typedef __attribute__((ext_vector_type(4))) float floatx4;
typedef __attribute__((ext_vector_type(4))) int intx4;

#define IDXMASK 0xFFFFF

// decode 8 signed bytes (as int2) -> 8 floats
__device__ __forceinline__ void sb8d(int2 q, float (&f)[8]) {
#pragma unroll
    for (int t = 0; t < 4; ++t) f[t] = (float)((q.x << (24 - 8 * t)) >> 24);
#pragma unroll
    for (int t = 0; t < 4; ++t) f[4 + t] = (float)((q.y << (24 - 8 * t)) >> 24);
}

// count(boundaries < x): analytic seed + shuffle-verified walk vs the real
// table values (lane L holds boundaries[L]); exact for |seed error| <= 2.
__device__ __forceinline__ int bucketize(float x, float bnd) {
    int i = (int)(x * 31.5f);           // boundaries ~ j/31.5
    i = min(max(i, 0), 64);
#pragma unroll
    for (int t = 0; t < 3; ++t) {
        float bi = __shfl(bnd, min(i, 63));
        if (i < 64 && bi < x) ++i;
    }
#pragma unroll
    for (int t = 0; t < 2; ++t) {
        float bim = __shfl(bnd, max(i - 1, 0));
        if (i > 0 && bim >= x) --i;
    }
    return i;
}

// fused prep: zero rst+degs+gctr, P = f16(embed @ G_w.T), int8-quantize feat
__global__ void k_prep(const float* __restrict__ Etab,
                       const float* __restrict__ G, _Float16* __restrict__ Ph,
                       float* __restrict__ rst, float* __restrict__ degs,
                       const float* __restrict__ feat,
                       signed char* __restrict__ featQ,
                       float* __restrict__ scaleQ, int* __restrict__ gctr,
                       int nRst, int nDeg) {
    int i = blockIdx.x * blockDim.x + threadIdx.x;
    if (i == 0 && gctr) gctr[0] = 0;
    if (i < nDeg) degs[i] = 0.0f;
    if (i < 65 * DFEAT) {
        int b = i >> 6, o = i & 63;
        float a = 0.0f;
#pragma unroll
        for (int m = 0; m < 32; ++m)
            a = fmaf(Etab[b * 32 + m], G[o * 32 + m], a);
        Ph[i] = (_Float16)a;
    }
    if (i < nRst) {
        __builtin_nontemporal_store(0.0f, rst + i);
        if (featQ) {   // wave == row (nRst multiple of 256, waves aligned)
            float f = feat[i];
            float a = fabsf(f);
#pragma unroll
            for (int o = 32; o; o >>= 1) a = fmaxf(a, __shfl_xor(a, o));
            float inv = (a > 0.0f) ? 127.0f / a : 0.0f;
            __builtin_nontemporal_store(
                (signed char)__float2int_rn(f * inv), featQ + i);
            if ((i & 63) == 0) scaleQ[i >> 6] = a * (1.0f / 127.0f);
        }
    }
}

__global__ void k_deg(const int* __restrict__ src, const int* __restrict__ dst,
                      float* __restrict__ degs, int N, int E) {
    int i = blockIdx.x * blockDim.x + threadIdx.x;
    if (i < E) {
        atomicAdd(&degs[dst[i]], 1.0f);       // in-deg
        atomicAdd(&degs[N + src[i]], 1.0f);   // out-deg
    }
}

// ---- 2-kernel parallel exclusive scan of in-deg -> binptr ----------------
#define SCHUNK 1024

__global__ void k_scanA(const float* __restrict__ degs, int* __restrict__ bsum,
                        int N) {
    __shared__ int part[256];
    const int t = threadIdx.x;
    const int base = blockIdx.x * SCHUNK + t * 4;
    int s = 0;
#pragma unroll
    for (int j = 0; j < 4; ++j) {
        int i = base + j;
        if (i < N) s += (int)degs[i];
    }
    part[t] = s;
    __syncthreads();
    for (int off = 128; off; off >>= 1) {
        if (t < off) part[t] += part[t + off];
        __syncthreads();
    }
    if (t == 0) bsum[blockIdx.x] = part[0];
}

// scanC with fused top-scan: block prefixes the NB partials from LDS.
__global__ void k_scanC(const float* __restrict__ degs,
                        const int* __restrict__ bsum, int* __restrict__ binptr,
                        int N, int NB) {
    __shared__ int part[256];
    __shared__ int sb[1024];
    __shared__ int basep;
    const int t = threadIdx.x;
    for (int i = t; i < NB; i += 256) sb[i] = bsum[i];
    const int base = blockIdx.x * SCHUNK + t * 4;
    int c[4];
    int s = 0;
#pragma unroll
    for (int j = 0; j < 4; ++j) {
        int i = base + j;
        c[j] = (i < N) ? (int)degs[i] : 0;
        s += c[j];
    }
    part[t] = s;
    __syncthreads();
    if (t == 0) {
        int run = 0;
        for (int i = 0; i < blockIdx.x; ++i) run += sb[i];
        basep = run;
    }
    // Hillis-Steele inclusive scan across the 256 thread-sums
    for (int off = 1; off < 256; off <<= 1) {
        int v = (t >= off) ? part[t - off] : 0;
        __syncthreads();
        part[t] += v;
        __syncthreads();
    }
    int run = basep + part[t] - s;   // exclusive prefix
#pragma unroll
    for (int j = 0; j < 4; ++j) {
        int i = base + j;
        if (i < N) {
            binptr[i] = run;
            run += c[j];
        }
    }
}

// scatter: full FRONT per edge (loc gathers, degs, 6 bucketizes, dsc),
// packed into one 32B dst-sorted record:
//   w0 = src | b1<<20, w1 = dst, w2..6 = ij | bj<<20, w7 = bits(dsc)
__global__ void k_scatter(const int* __restrict__ src,
                          const int* __restrict__ dst,
                          const int* __restrict__ inter,
                          const float* __restrict__ loc,
                          const float* __restrict__ degs,
                          const float* __restrict__ bnds,
                          int* __restrict__ binptr, int* __restrict__ pack,
                          int N, int E, int paddedE) {
    const int i = blockIdx.x * blockDim.x + threadIdx.x;
    const float bnd = bnds[threadIdx.x & 63];   // before divergence (shfl src)
    if (i < E) {
        const int s = src[i];
        const int dd = dst[i];
        const float2 ls = ((const float2*)loc)[s];
        const float2 ld = ((const float2*)loc)[dd];
        const float dsc = rsqrtf(fmaxf(degs[dd], 1.0f)) *
                          rsqrtf(fmaxf(degs[N + s], 1.0f));
        float dx = ld.x - ls.x, dy = ld.y - ls.y;
        const int b1 = bucketize(sqrtf(dx * dx + dy * dy), bnd);
        int w2[5];
#pragma unroll
        for (int j = 0; j < 5; ++j) {
            int id = inter[i * 5 + j];
            float2 lj = ((const float2*)loc)[id];
            float ex = ls.x - lj.x, ey = ls.y - lj.y;
            int bj = bucketize(sqrtf(ex * ex + ey * ey), bnd);
            w2[j] = id | (bj << 20);
        }
        int pos = atomicAdd(&binptr[dd], 1);
        intx4 p0 = {s | (b1 << 20), dd, w2[0], w2[1]};
        intx4 p1 = {w2[2], w2[3], w2[4], __float_as_int(dsc)};
        __builtin_nontemporal_store(p0, (intx4*)(pack + (size_t)pos * 8));
        __builtin_nontemporal_store(p1, (intx4*)(pack + (size_t)pos * 8 + 4));
    } else if (i < paddedE) {
        intx4 z = {0, 0, 0, 0};   // dsc=0 -> padded lanes contribute nothing
        __builtin_nontemporal_store(z, (intx4*)(pack + (size_t)i * 8));
        __builtin_nontemporal_store(z, (intx4*)(pack + (size_t)i * 8 + 4));
    }
}

#define PPADH 72  // sPh row stride (f16): 144B = 36 dwords -> 4-bank row shift

__global__ __launch_bounds__(256, 6) void k_edge(
    const float* __restrict__ feat, const signed char* __restrict__ featQ,
    const float* __restrict__ scaleQ, const float* __restrict__ loc,
    const float* __restrict__ agg_w, const float* __restrict__ agg_b,
    const float* __restrict__ bnds, const int* __restrict__ src,
    const int* __restrict__ dst, const int* __restrict__ inter,
    const int* __restrict__ pack, const _Float16* __restrict__ Ph,
    const float* __restrict__ degs, int* __restrict__ gctr,
    float* __restrict__ rst, int N, int E) {
    const int tid = threadIdx.x;
    const int lane = tid & 63;
    const int wid = tid >> 6;
    const int m16 = lane & 15;
    const int quad = lane >> 4;

    __shared__ _Float16 sPh[65 * PPADH];  // 9360 B
    __shared__ half8 sWB[16 * 64];        // 16384 B  -> total 25744 B, 6/CU

    for (int i = tid; i < 65 * DFEAT; i += 256)
        sPh[(i >> 6) * PPADH + (i & 63)] = Ph[i];

    // B-fragment fill: frag f = slab*4+ntile; lane holds n=nt*16+m16,
    // k = slab*32 + quad*8 + j  (B[k][n] = W^T[k][n] = W[n][k])
    for (int f = wid; f < 16; f += 4) {
        int sl = f >> 2, nt = f & 3;
        const float* wp = agg_w + (nt * 16 + m16) * 128 + sl * 32 + quad * 8;
        floatx4 wa = *(const floatx4*)wp;
        floatx4 wb = *(const floatx4*)(wp + 4);
        float xs[8] = {wa.x, wa.y, wa.z, wa.w, wb.x, wb.y, wb.z, wb.w};
        half8 h;
#pragma unroll
        for (int j = 0; j < 8; ++j) h[j] = (_Float16)xs[j];
        sWB[f * 64 + lane] = h;
    }

    const float bnd = bnds[lane];
    float bias4[4];
#pragma unroll
    for (int nt = 0; nt < 4; ++nt) bias4[nt] = agg_b[nt * 16 + m16];

    __syncthreads();

    const int nw = gridDim.x << 2;
    const int wi = (blockIdx.x << 2) + wid;
    const int ngroups = (E + 15) >> 4;
    const int k0q = quad * 8;

    int gs = wi;                 // static cursor (fallback path only)

    for (;;) {
        int g;
        if (pack) {              // work-steal: balances the 4-vs-5 tail
            int gp = 0;
            if (lane == 0) gp = atomicAdd(gctr, 1);
            g = __shfl(gp, 0);
        } else {
            g = gs;
            gs += nw;
        }
        if (g >= ngroups) break;

        const int em = (g << 4) + m16;        // this lane's edge (dup x4)

        int s, d, b1, ij[5], bj[5];
        float dsc;
        half8 A[4];

        if (pack) {
            // ---- B1: one 32B record, front precomputed in k_scatter -------
            const intx4 p0 = __builtin_nontemporal_load(
                (const intx4*)(pack + (size_t)em * 8));  // em < paddedE safe
            const intx4 p1 = __builtin_nontemporal_load(
                (const intx4*)(pack + (size_t)em * 8 + 4));
            s = p0[0] & IDXMASK;  b1 = p0[0] >> 20;
            d = p0[1];
            ij[0] = p0[2] & IDXMASK; bj[0] = p0[2] >> 20;
            ij[1] = p0[3] & IDXMASK; bj[1] = p0[3] >> 20;
            ij[2] = p1[0] & IDXMASK; bj[2] = p1[0] >> 20;
            ij[3] = p1[1] & IDXMASK; bj[3] = p1[1] >> 20;
            ij[4] = p1[2] & IDXMASK; bj[4] = p1[2] >> 20;
            dsc = __int_as_float(p1[3]);    // 0 for padded records

            const float ssrc = scaleQ[s];
            float sq[5];
#pragma unroll
            for (int j = 0; j < 5; ++j) sq[j] = scaleQ[ij[j]];

            // ---- B3: all 12 featQ gathers ---------------------------------
            const signed char* qrow = featQ + (s << 6);
            int2 qu[2];
            qu[0] = *(const int2*)(qrow + k0q);
            qu[1] = *(const int2*)(qrow + 32 + k0q);
            int2 qv[2][5];
#pragma unroll
            for (int sl = 0; sl < 2; ++sl)
#pragma unroll
                for (int j = 0; j < 5; ++j)
                    qv[sl][j] =
                        *(const int2*)(featQ + (ij[j] << 6) + sl * 32 + k0q);

            // ---- decode u: cat[k<64] = int8 src row * scale * P[b1] -------
            const _Float16* prow = sPh + b1 * PPADH;
#pragma unroll
            for (int sl = 0; sl < 2; ++sl) {
                int k0 = sl * 32 + k0q;
                float fq[8];
                sb8d(qu[sl], fq);
                half8 ph = *(const half8*)(prow + k0);
                half8 h;
#pragma unroll
                for (int j = 0; j < 8; ++j)
                    h[j] = (_Float16)(fq[j] * ssrc * (float)ph[j]);
                A[sl] = h;
            }
            // ---- decode v: cat[k>=64] = mean of 5 scaled rows * P[bj] -----
#pragma unroll
            for (int sl = 0; sl < 2; ++sl) {
                int k0 = sl * 32 + k0q;
                float r[8] = {0, 0, 0, 0, 0, 0, 0, 0};
#pragma unroll
                for (int j = 0; j < 5; ++j) {
                    float fq[8];
                    sb8d(qv[sl][j], fq);
                    const float sj = sq[j];
                    half8 pv = *(const half8*)(sPh + bj[j] * PPADH + k0);
                    r[0] = fmaf(fq[0] * sj, (float)pv[0], r[0]);
                    r[1] = fmaf(fq[1] * sj, (float)pv[1], r[1]);
                    r[2] = fmaf(fq[2] * sj, (float)pv[2], r[2]);
                    r[3] = fmaf(fq[3] * sj, (float)pv[3], r[3]);
                    r[4] = fmaf(fq[4] * sj, (float)pv[4], r[4]);
                    r[5] = fmaf(fq[5] * sj, (float)pv[5], r[5]);
                    r[6] = fmaf(fq[6] * sj, (float)pv[6], r[6]);
                    r[7] = fmaf(fq[7] * sj, (float)pv[7], r[7]);
                }
                half8 h;
#pragma unroll
                for (int j = 0; j < 8; ++j) h[j] = (_Float16)(r[j] * 0.2f);
                A[2 + sl] = h;
            }
        } else {
            // fallback (no workspace / N too large): full front in-kernel
            const bool act = em < E;
            const int ec = act ? em : 0;
            s = src[ec];
            d = dst[ec];
            const float2 ls = ((const float2*)loc)[s];
            const float2 ld = ((const float2*)loc)[d];
            dsc = rsqrtf(fmaxf(degs[d], 1.0f)) *
                  rsqrtf(fmaxf(degs[N + s], 1.0f));
            if (!act) dsc = 0.0f;
            float dx = ld.x - ls.x, dy = ld.y - ls.y;
            b1 = bucketize(sqrtf(dx * dx + dy * dy), bnd);
#pragma unroll
            for (int j = 0; j < 5; ++j) {
                int id = inter[ec * 5 + j];
                ij[j] = id;
                float2 lj = ((const float2*)loc)[id];
                float ex = ls.x - lj.x, ey = ls.y - lj.y;
                bj[j] = bucketize(sqrtf(ex * ex + ey * ey), bnd);
            }
            const float* frow = feat + (s << 6);
            const _Float16* prow = sPh + b1 * PPADH;
#pragma unroll
            for (int sl = 0; sl < 2; ++sl) {
                int k0 = sl * 32 + k0q;
                floatx4 fa = *(const floatx4*)(frow + k0);
                floatx4 fb = *(const floatx4*)(frow + k0 + 4);
                half8 ph = *(const half8*)(prow + k0);
                float xs[8] = {fa.x * (float)ph[0], fa.y * (float)ph[1],
                               fa.z * (float)ph[2], fa.w * (float)ph[3],
                               fb.x * (float)ph[4], fb.y * (float)ph[5],
                               fb.z * (float)ph[6], fb.w * (float)ph[7]};
                half8 h;
#pragma unroll
                for (int j = 0; j < 8; ++j) h[j] = (_Float16)xs[j];
                A[sl] = h;
            }
#pragma unroll
            for (int sl = 0; sl < 2; ++sl) {
                int k0 = sl * 32 + k0q;
                float r[8] = {0, 0, 0, 0, 0, 0, 0, 0};
#pragma unroll
                for (int j = 0; j < 5; ++j) {
                    const float* fr = feat + (ij[j] << 6);
                    floatx4 fa = *(const floatx4*)(fr + k0);
                    floatx4 fb = *(const floatx4*)(fr + k0 + 4);
                    half8 pv = *(const half8*)(sPh + bj[j] * PPADH + k0);
                    r[0] = fmaf(fa.x, (float)pv[0], r[0]);
                    r[1] = fmaf(fa.y, (float)pv[1], r[1]);
                    r[2] = fmaf(fa.z, (float)pv[2], r[2]);
                    r[3] = fmaf(fa.w, (float)pv[3], r[3]);
                    r[4] = fmaf(fb.x, (float)pv[4], r[4]);
                    r[5] = fmaf(fb.y, (float)pv[5], r[5]);
                    r[6] = fmaf(fb.z, (float)pv[6], r[6]);
                    r[7] = fmaf(fb.w, (float)pv[7], r[7]);
                }
                half8 h;
#pragma unroll
                for (int j = 0; j < 8; ++j) h[j] = (_Float16)(r[j] * 0.2f);
                A[2 + sl] = h;
            }
        }

        // ---- MFMA: 4 k-slabs x 4 n-tiles, single f16 product --------------
        floatx4 acc[4] = {{0, 0, 0, 0}, {0, 0, 0, 0}, {0, 0, 0, 0}, {0, 0, 0, 0}};
#pragma unroll
        for (int sl = 0; sl < 4; ++sl) {
#pragma unroll
            for (int nt = 0; nt < 4; ++nt) {
                half8 b = sWB[((sl << 2) + nt) * 64 + lane];
                acc[nt] = __builtin_amdgcn_mfma_f32_16x16x32_f16(
                    A[sl], b, acc[nt], 0, 0, 0);
            }
        }

        // ---- merged epilogue: dst-sorted => equal-dst runs among the 16 ---
        const int q4 = quad << 2;
        const int dm0 = __shfl(d, q4 + 0), dm1 = __shfl(d, q4 + 1);
        const int dm2 = __shfl(d, q4 + 2), dm3 = __shfl(d, q4 + 3);
        const float sc0 = __shfl(dsc, q4 + 0), sc1 = __shfl(dsc, q4 + 1);
        const float sc2 = __shfl(dsc, q4 + 2), sc3 = __shfl(dsc, q4 + 3);
        const int dmn = __shfl(d, (q4 + 4) & 15);
        const int dmp = __shfl(d, (q4 - 1) & 15);
        const bool eq0 = dm0 == dm1, eq1 = dm1 == dm2, eq2 = dm2 == dm3;
        const bool eq3 = (quad < 3) && (dm3 == dmn);
        const bool lnk = (quad > 0) && (dmp == dm0);
        const bool alls = eq0 && eq1 && eq2;
        const bool gate = alls && lnk;

        float w0[4], w1[4], w2[4], w3[4], Ci[4];
#pragma unroll
        for (int nt = 0; nt < 4; ++nt) {
            w0[nt] = (acc[nt][0] + bias4[nt]) * sc0;
            w1[nt] = (acc[nt][1] + bias4[nt]) * sc1;
            w2[nt] = (acc[nt][2] + bias4[nt]) * sc2;
            w3[nt] = (acc[nt][3] + bias4[nt]) * sc3;
            if (eq0) w1[nt] += w0[nt];
            if (eq1) w2[nt] += w1[nt];
            if (eq2) w3[nt] += w2[nt];
            float T = w3[nt];
#pragma unroll
            for (int k = 0; k < 3; ++k) {
                float Tp = __shfl(T, (lane - 16) & 63);
                T = w3[nt] + (gate ? Tp : 0.0f);
            }
            float c = __shfl(T, (lane - 16) & 63);
            Ci[nt] = lnk ? c : 0.0f;
        }

        if (!eq0) {
            float* ap = rst + (dm0 << 6) + m16;
            float v0 = w0[0] + Ci[0], v1 = w0[1] + Ci[1];
            float v2 = w0[2] + Ci[2], v3 = w0[3] + Ci[3];
            asm volatile("global_atomic_add_f32 %0, %1, off nt" :: "v"(ap), "v"(v0));
            asm volatile("global_atomic_add_f32 %0, %1, off offset:64 nt" :: "v"(ap), "v"(v1));
            asm volatile("global_atomic_add_f32 %0, %1, off offset:128 nt" :: "v"(ap), "v"(v2));
            asm volatile("global_atomic_add_f32 %0, %1, off offset:192 nt" :: "v"(ap), "v"(v3));
        }
        if (!eq1) {
            float* ap = rst + (dm1 << 6) + m16;
            float h0 = eq0 ? Ci[0] : 0.0f, h1 = eq0 ? Ci[1] : 0.0f;
            float h2 = eq0 ? Ci[2] : 0.0f, h3 = eq0 ? Ci[3] : 0.0f;
            float v0 = w1[0] + h0, v1 = w1[1] + h1;
            float v2 = w1[2] + h2, v3 = w1[3] + h3;
            asm volatile("global_atomic_add_f32 %0, %1, off nt" :: "v"(ap), "v"(v0));
            asm volatile("global_atomic_add_f32 %0, %1, off offset:64 nt" :: "v"(ap), "v"(v1));
            asm volatile("global_atomic_add_f32 %0, %1, off offset:128 nt" :: "v"(ap), "v"(v2));
            asm volatile("global_atomic_add_f32 %0, %1, off offset:192 nt" :: "v"(ap), "v"(v3));
        }
        if (!eq2) {
            const bool hr = eq0 && eq1;
            float* ap = rst + (dm2 << 6) + m16;
            float v0 = w2[0] + (hr ? Ci[0] : 0.0f), v1 = w2[1] + (hr ? Ci[1] : 0.0f);
            float v2 = w2[2] + (hr ? Ci[2] : 0.0f), v3 = w2[3] + (hr ? Ci[3] : 0.0f);
            asm volatile("global_atomic_add_f32 %0, %1, off nt" :: "v"(ap), "v"(v0));
            asm volatile("global_atomic_add_f32 %0, %1, off offset:64 nt" :: "v"(ap), "v"(v1));
            asm volatile("global_atomic_add_f32 %0, %1, off offset:128 nt" :: "v"(ap), "v"(v2));
            asm volatile("global_atomic_add_f32 %0, %1, off offset:192 nt" :: "v"(ap), "v"(v3));
        }
        if (!eq3) {
            float* ap = rst + (dm3 << 6) + m16;
            float v0 = w3[0] + (alls ? Ci[0] : 0.0f), v1 = w3[1] + (alls ? Ci[1] : 0.0f);
            float v2 = w3[2] + (alls ? Ci[2] : 0.0f), v3 = w3[3] + (alls ? Ci[3] : 0.0f);
            asm volatile("global_atomic_add_f32 %0, %1, off nt" :: "v"(ap), "v"(v0));
            asm volatile("global_atomic_add_f32 %0, %1, off offset:64 nt" :: "v"(ap), "v"(v1));
            asm volatile("global_atomic_add_f32 %0, %1, off offset:128 nt" :: "v"(ap), "v"(v2));
            asm volatile("global_atomic_add_f32 %0, %1, off offset:192 nt" :: "v"(ap), "v"(v3));
        }
    }
}

extern "C" void kernel_launch(void* const* d_in, const int* in_sizes, int n_in,
                              void* d_out, int out_size, void* d_ws,
                              size_t ws_size, hipStream_t stream) {
    const float* feat  = (const float*)d_in[0];
    const float* loc   = (const float*)d_in[1];
    const float* embed = (const float*)d_in[2];
    const float* G_w   = (const float*)d_in[3];
    const float* agg_w = (const float*)d_in[4];
    const float* agg_b = (const float*)d_in[5];
    const float* bnds  = (const float*)d_in[6];
    const int* src   = (const int*)d_in[7];
    const int* dst   = (const int*)d_in[8];
    const int* inter = (const int*)d_in[9];

    const int N = in_sizes[0] / DFEAT;
    const int E = in_sizes[7];
    const int ngroups = (E + 15) >> 4;
    const int paddedE = ngroups << 4;
    const int NB = (N + SCHUNK - 1) / SCHUNK;

    float* rst = (float*)d_out;
    char* wsb = (char*)d_ws;

    auto al16 = [](size_t x) { return (x + 15) & ~(size_t)15; };
    size_t off_degs = 0;
    size_t off_p = al16(off_degs + 2 * (size_t)N * 4);
    size_t off_scale = al16(off_p + 65 * DFEAT * 2);
    size_t off_q = al16(off_scale + (size_t)N * 4);
    size_t off_bin = al16(off_q + (size_t)N * DFEAT);
    size_t off_pack = al16(off_bin + (size_t)N * 4);
    size_t off_bsum = off_pack + 32 * (size_t)paddedE;
    size_t off_gctr = al16(off_bsum + (size_t)NB * 4);
    size_t need_all = off_gctr + 16;

    float* degs = (float*)(wsb + off_degs);
    _Float16* Ph = (_Float16*)(wsb + off_p);
    float* scaleQ = (float*)(wsb + off_scale);
    signed char* featQ =
        (ws_size >= off_bin) ? (signed char*)(wsb + off_q) : nullptr;
    int* binptr = nullptr;
    int* pack = nullptr;
    int* bsum = nullptr;
    int* gctr = nullptr;
    if (ws_size >= need_all && N < (1 << 20) && NB <= 1024 && featQ) {
        binptr = (int*)(wsb + off_bin);
        pack = (int*)(wsb + off_pack);
        bsum = (int*)(wsb + off_bsum);
        gctr = (int*)(wsb + off_gctr);
    }

    const int nRst = N * DFEAT;
    const int nDeg = 2 * N;

    k_prep<<<(nRst + 255) / 256, 256, 0, stream>>>(
        embed, G_w, Ph, rst, degs, feat, featQ, scaleQ, gctr, nRst, nDeg);
    k_deg<<<(E + 255) / 256, 256, 0, stream>>>(src, dst, degs, N, E);
    if (pack) {
        k_scanA<<<NB, 256, 0, stream>>>(degs, bsum, N);
        k_scanC<<<NB, 256, 0, stream>>>(degs, bsum, binptr, N, NB);
        k_scatter<<<(paddedE + 255) / 256, 256, 0, stream>>>(
            src, dst, inter, loc, degs, bnds, binptr, pack, N, E, paddedE);
    }
    // LDS 25744 B/block -> 6 blocks/CU (24 waves); 1536 blocks resident.
    // Work-steal pop balances the 4-vs-5 group tail (424/6144 waves).
    k_edge<<<1536, 256, 0, stream>>>(feat, featQ, scaleQ, loc, agg_w, agg_b,
                                     bnds, src, dst, inter, pack, Ph, degs,
                                     gctr, rst, N, E);
}

// Round 18
// 251.302 us; speedup vs baseline: 2.1650x; 2.1650x over previous
//
#include <hip/hip_runtime.h>

// SpatialEvoProp — R21: exact R17 revert (session best: 255.9us) + R20's
// neutral fused scan (one fewer launch). R20's work-steal was catastrophic
// (k_edge 84.5->375us): a per-wave-iteration GLOBAL atomic pop serializes
// across 8 non-coherent-L2 XCDs (~25k contended RMWs in the critical path).
// POISONED: global work-stealing at wave granularity. Static contiguous
// chunks restored (4-vs-5 tail ~16us is accepted; no safe fix exists).
// Session levers, all tested to falsification: occupancy (R18 lb(256,8)
// spills; R19 sP-from-global L1-thrash), ILP (R5/R10/R12 compiler pins
// VGPR), traffic (R9 nt atomics: FETCH 503->37MB, THE win), atomic count
// (R13 merge: 25.6M->3.5M, k_edge 135->90), sort cost (R16 parallel scan),
// front placement (R17 scatter-front + f16 sP: 90->84.5).
// Remaining: k_edge 84.5 (latency chain @ 50% occ) + sort ~43 + fixed ~128.

#define DFEAT 64

typedef __attribute__((ext_vector_type(8))) _Float16 half8;
typedef __attribute__((ext_vector_type(4))) float floatx4;
typedef __attribute__((ext_vector_type(4))) int intx4;

#define IDXMASK 0xFFFFF

// decode 8 signed bytes (as int2) -> 8 floats
__device__ __forceinline__ void sb8d(int2 q, float (&f)[8]) {
#pragma unroll
    for (int t = 0; t < 4; ++t) f[t] = (float)((q.x << (24 - 8 * t)) >> 24);
#pragma unroll
    for (int t = 0; t < 4; ++t) f[4 + t] = (float)((q.y << (24 - 8 * t)) >> 24);
}

// count(boundaries < x): analytic seed + shuffle-verified walk vs the real
// table values (lane L holds boundaries[L]); exact for |seed error| <= 2.
__device__ __forceinline__ int bucketize(float x, float bnd) {
    int i = (int)(x * 31.5f);           // boundaries ~ j/31.5
    i = min(max(i, 0), 64);
#pragma unroll
    for (int t = 0; t < 3; ++t) {
        float bi = __shfl(bnd, min(i, 63));
        if (i < 64 && bi < x) ++i;
    }
#pragma unroll
    for (int t = 0; t < 2; ++t) {
        float bim = __shfl(bnd, max(i - 1, 0));
        if (i > 0 && bim >= x) --i;
    }
    return i;
}

// fused prep: zero rst+degs, P = f16(embed @ G_w.T), int8-quantize feat rows
__global__ void k_prep(const float* __restrict__ Etab,
                       const float* __restrict__ G, _Float16* __restrict__ Ph,
                       float* __restrict__ rst, float* __restrict__ degs,
                       const float* __restrict__ feat,
                       signed char* __restrict__ featQ,
                       float* __restrict__ scaleQ, int nRst, int nDeg) {
    int i = blockIdx.x * blockDim.x + threadIdx.x;
    if (i < nDeg) degs[i] = 0.0f;
    if (i < 65 * DFEAT) {
        int b = i >> 6, o = i & 63;
        float a = 0.0f;
#pragma unroll
        for (int m = 0; m < 32; ++m)
            a = fmaf(Etab[b * 32 + m], G[o * 32 + m], a);
        Ph[i] = (_Float16)a;
    }
    if (i < nRst) {
        __builtin_nontemporal_store(0.0f, rst + i);
        if (featQ) {   // wave == row (nRst multiple of 256, waves aligned)
            float f = feat[i];
            float a = fabsf(f);
#pragma unroll
            for (int o = 32; o; o >>= 1) a = fmaxf(a, __shfl_xor(a, o));
            float inv = (a > 0.0f) ? 127.0f / a : 0.0f;
            __builtin_nontemporal_store(
                (signed char)__float2int_rn(f * inv), featQ + i);
            if ((i & 63) == 0) scaleQ[i >> 6] = a * (1.0f / 127.0f);
        }
    }
}

__global__ void k_deg(const int* __restrict__ src, const int* __restrict__ dst,
                      float* __restrict__ degs, int N, int E) {
    int i = blockIdx.x * blockDim.x + threadIdx.x;
    if (i < E) {
        atomicAdd(&degs[dst[i]], 1.0f);       // in-deg
        atomicAdd(&degs[N + src[i]], 1.0f);   // out-deg
    }
}

// ---- 2-kernel parallel exclusive scan of in-deg -> binptr ----------------
#define SCHUNK 1024

__global__ void k_scanA(const float* __restrict__ degs, int* __restrict__ bsum,
                        int N) {
    __shared__ int part[256];
    const int t = threadIdx.x;
    const int base = blockIdx.x * SCHUNK + t * 4;
    int s = 0;
#pragma unroll
    for (int j = 0; j < 4; ++j) {
        int i = base + j;
        if (i < N) s += (int)degs[i];
    }
    part[t] = s;
    __syncthreads();
    for (int off = 128; off; off >>= 1) {
        if (t < off) part[t] += part[t + off];
        __syncthreads();
    }
    if (t == 0) bsum[blockIdx.x] = part[0];
}

// scanC with fused top-scan: block prefixes the NB partials from LDS.
__global__ void k_scanC(const float* __restrict__ degs,
                        const int* __restrict__ bsum, int* __restrict__ binptr,
                        int N, int NB) {
    __shared__ int part[256];
    __shared__ int sb[1024];
    __shared__ int basep;
    const int t = threadIdx.x;
    for (int i = t; i < NB; i += 256) sb[i] = bsum[i];
    const int base = blockIdx.x * SCHUNK + t * 4;
    int c[4];
    int s = 0;
#pragma unroll
    for (int j = 0; j < 4; ++j) {
        int i = base + j;
        c[j] = (i < N) ? (int)degs[i] : 0;
        s += c[j];
    }
    part[t] = s;
    __syncthreads();
    if (t == 0) {
        int run = 0;
        for (int i = 0; i < blockIdx.x; ++i) run += sb[i];
        basep = run;
    }
    // Hillis-Steele inclusive scan across the 256 thread-sums
    for (int off = 1; off < 256; off <<= 1) {
        int v = (t >= off) ? part[t - off] : 0;
        __syncthreads();
        part[t] += v;
        __syncthreads();
    }
    int run = basep + part[t] - s;   // exclusive prefix
#pragma unroll
    for (int j = 0; j < 4; ++j) {
        int i = base + j;
        if (i < N) {
            binptr[i] = run;
            run += c[j];
        }
    }
}

// scatter: full FRONT per edge (loc gathers, degs, 6 bucketizes, dsc),
// packed into one 32B dst-sorted record:
//   w0 = src | b1<<20, w1 = dst, w2..6 = ij | bj<<20, w7 = bits(dsc)
__global__ void k_scatter(const int* __restrict__ src,
                          const int* __restrict__ dst,
                          const int* __restrict__ inter,
                          const float* __restrict__ loc,
                          const float* __restrict__ degs,
                          const float* __restrict__ bnds,
                          int* __restrict__ binptr, int* __restrict__ pack,
                          int N, int E, int paddedE) {
    const int i = blockIdx.x * blockDim.x + threadIdx.x;
    const float bnd = bnds[threadIdx.x & 63];   // before divergence (shfl src)
    if (i < E) {
        const int s = src[i];
        const int dd = dst[i];
        const float2 ls = ((const float2*)loc)[s];
        const float2 ld = ((const float2*)loc)[dd];
        const float dsc = rsqrtf(fmaxf(degs[dd], 1.0f)) *
                          rsqrtf(fmaxf(degs[N + s], 1.0f));
        float dx = ld.x - ls.x, dy = ld.y - ls.y;
        const int b1 = bucketize(sqrtf(dx * dx + dy * dy), bnd);
        int w2[5];
#pragma unroll
        for (int j = 0; j < 5; ++j) {
            int id = inter[i * 5 + j];
            float2 lj = ((const float2*)loc)[id];
            float ex = ls.x - lj.x, ey = ls.y - lj.y;
            int bj = bucketize(sqrtf(ex * ex + ey * ey), bnd);
            w2[j] = id | (bj << 20);
        }
        int pos = atomicAdd(&binptr[dd], 1);
        intx4 p0 = {s | (b1 << 20), dd, w2[0], w2[1]};
        intx4 p1 = {w2[2], w2[3], w2[4], __float_as_int(dsc)};
        __builtin_nontemporal_store(p0, (intx4*)(pack + (size_t)pos * 8));
        __builtin_nontemporal_store(p1, (intx4*)(pack + (size_t)pos * 8 + 4));
    } else if (i < paddedE) {
        intx4 z = {0, 0, 0, 0};   // dsc=0 -> padded lanes contribute nothing
        __builtin_nontemporal_store(z, (intx4*)(pack + (size_t)i * 8));
        __builtin_nontemporal_store(z, (intx4*)(pack + (size_t)i * 8 + 4));
    }
}

#define PPADH 72  // sPh row stride (f16): 144B = 36 dwords -> 4-bank row shift

__global__ __launch_bounds__(256, 6) void k_edge(
    const float* __restrict__ feat, const signed char* __restrict__ featQ,
    const float* __restrict__ scaleQ, const float* __restrict__ loc,
    const float* __restrict__ agg_w, const float* __restrict__ agg_b,
    const float* __restrict__ bnds, const int* __restrict__ src,
    const int* __restrict__ dst, const int* __restrict__ inter,
    const int* __restrict__ pack, const _Float16* __restrict__ Ph,
    const float* __restrict__ degs, float* __restrict__ rst, int N, int E) {
    const int tid = threadIdx.x;
    const int lane = tid & 63;
    const int wid = tid >> 6;
    const int m16 = lane & 15;
    const int quad = lane >> 4;

    __shared__ _Float16 sPh[65 * PPADH];  // 9360 B
    __shared__ half8 sWB[16 * 64];        // 16384 B  -> total 25744 B, 6/CU

    for (int i = tid; i < 65 * DFEAT; i += 256)
        sPh[(i >> 6) * PPADH + (i & 63)] = Ph[i];

    // B-fragment fill: frag f = slab*4+ntile; lane holds n=nt*16+m16,
    // k = slab*32 + quad*8 + j  (B[k][n] = W^T[k][n] = W[n][k])
    for (int f = wid; f < 16; f += 4) {
        int sl = f >> 2, nt = f & 3;
        const float* wp = agg_w + (nt * 16 + m16) * 128 + sl * 32 + quad * 8;
        floatx4 wa = *(const floatx4*)wp;
        floatx4 wb = *(const floatx4*)(wp + 4);
        float xs[8] = {wa.x, wa.y, wa.z, wa.w, wb.x, wb.y, wb.z, wb.w};
        half8 h;
#pragma unroll
        for (int j = 0; j < 8; ++j) h[j] = (_Float16)xs[j];
        sWB[f * 64 + lane] = h;
    }

    const float bnd = bnds[lane];
    float bias4[4];
#pragma unroll
    for (int nt = 0; nt < 4; ++nt) bias4[nt] = agg_b[nt * 16 + m16];

    __syncthreads();

    const int nw = gridDim.x << 2;
    const int wi = (blockIdx.x << 2) + wid;
    const int ngroups = (E + 15) >> 4;
    const int k0q = quad * 8;

    // contiguous balanced chunks: preserves dst-run locality per wave
    const int qq = ngroups / nw, rr = ngroups - qq * nw;
    const int g0 = wi * qq + min(wi, rr);
    const int g1 = g0 + qq + (wi < rr ? 1 : 0);

    for (int g = g0; g < g1; ++g) {
        const int em = (g << 4) + m16;        // this lane's edge (dup x4)

        int s, d, b1, ij[5], bj[5];
        float dsc;
        half8 A[4];

        if (pack) {
            // ---- B1: one 32B record, front precomputed in k_scatter -------
            const intx4 p0 = __builtin_nontemporal_load(
                (const intx4*)(pack + (size_t)em * 8));  // em < paddedE safe
            const intx4 p1 = __builtin_nontemporal_load(
                (const intx4*)(pack + (size_t)em * 8 + 4));
            s = p0[0] & IDXMASK;  b1 = p0[0] >> 20;
            d = p0[1];
            ij[0] = p0[2] & IDXMASK; bj[0] = p0[2] >> 20;
            ij[1] = p0[3] & IDXMASK; bj[1] = p0[3] >> 20;
            ij[2] = p1[0] & IDXMASK; bj[2] = p1[0] >> 20;
            ij[3] = p1[1] & IDXMASK; bj[3] = p1[1] >> 20;
            ij[4] = p1[2] & IDXMASK; bj[4] = p1[2] >> 20;
            dsc = __int_as_float(p1[3]);    // 0 for padded records

            const float ssrc = scaleQ[s];
            float sq[5];
#pragma unroll
            for (int j = 0; j < 5; ++j) sq[j] = scaleQ[ij[j]];

            // ---- B3: all 12 featQ gathers ---------------------------------
            const signed char* qrow = featQ + (s << 6);
            int2 qu[2];
            qu[0] = *(const int2*)(qrow + k0q);
            qu[1] = *(const int2*)(qrow + 32 + k0q);
            int2 qv[2][5];
#pragma unroll
            for (int sl = 0; sl < 2; ++sl)
#pragma unroll
                for (int j = 0; j < 5; ++j)
                    qv[sl][j] =
                        *(const int2*)(featQ + (ij[j] << 6) + sl * 32 + k0q);

            // ---- decode u: cat[k<64] = int8 src row * scale * P[b1] -------
            const _Float16* prow = sPh + b1 * PPADH;
#pragma unroll
            for (int sl = 0; sl < 2; ++sl) {
                int k0 = sl * 32 + k0q;
                float fq[8];
                sb8d(qu[sl], fq);
                half8 ph = *(const half8*)(prow + k0);
                half8 h;
#pragma unroll
                for (int j = 0; j < 8; ++j)
                    h[j] = (_Float16)(fq[j] * ssrc * (float)ph[j]);
                A[sl] = h;
            }
            // ---- decode v: cat[k>=64] = mean of 5 scaled rows * P[bj] -----
#pragma unroll
            for (int sl = 0; sl < 2; ++sl) {
                int k0 = sl * 32 + k0q;
                float r[8] = {0, 0, 0, 0, 0, 0, 0, 0};
#pragma unroll
                for (int j = 0; j < 5; ++j) {
                    float fq[8];
                    sb8d(qv[sl][j], fq);
                    const float sj = sq[j];
                    half8 pv = *(const half8*)(sPh + bj[j] * PPADH + k0);
                    r[0] = fmaf(fq[0] * sj, (float)pv[0], r[0]);
                    r[1] = fmaf(fq[1] * sj, (float)pv[1], r[1]);
                    r[2] = fmaf(fq[2] * sj, (float)pv[2], r[2]);
                    r[3] = fmaf(fq[3] * sj, (float)pv[3], r[3]);
                    r[4] = fmaf(fq[4] * sj, (float)pv[4], r[4]);
                    r[5] = fmaf(fq[5] * sj, (float)pv[5], r[5]);
                    r[6] = fmaf(fq[6] * sj, (float)pv[6], r[6]);
                    r[7] = fmaf(fq[7] * sj, (float)pv[7], r[7]);
                }
                half8 h;
#pragma unroll
                for (int j = 0; j < 8; ++j) h[j] = (_Float16)(r[j] * 0.2f);
                A[2 + sl] = h;
            }
        } else {
            // fallback (no workspace / N too large): full front in-kernel
            const bool act = em < E;
            const int ec = act ? em : 0;
            s = src[ec];
            d = dst[ec];
            const float2 ls = ((const float2*)loc)[s];
            const float2 ld = ((const float2*)loc)[d];
            dsc = rsqrtf(fmaxf(degs[d], 1.0f)) *
                  rsqrtf(fmaxf(degs[N + s], 1.0f));
            if (!act) dsc = 0.0f;
            float dx = ld.x - ls.x, dy = ld.y - ls.y;
            b1 = bucketize(sqrtf(dx * dx + dy * dy), bnd);
#pragma unroll
            for (int j = 0; j < 5; ++j) {
                int id = inter[ec * 5 + j];
                ij[j] = id;
                float2 lj = ((const float2*)loc)[id];
                float ex = ls.x - lj.x, ey = ls.y - lj.y;
                bj[j] = bucketize(sqrtf(ex * ex + ey * ey), bnd);
            }
            const float* frow = feat + (s << 6);
            const _Float16* prow = sPh + b1 * PPADH;
#pragma unroll
            for (int sl = 0; sl < 2; ++sl) {
                int k0 = sl * 32 + k0q;
                floatx4 fa = *(const floatx4*)(frow + k0);
                floatx4 fb = *(const floatx4*)(frow + k0 + 4);
                half8 ph = *(const half8*)(prow + k0);
                float xs[8] = {fa.x * (float)ph[0], fa.y * (float)ph[1],
                               fa.z * (float)ph[2], fa.w * (float)ph[3],
                               fb.x * (float)ph[4], fb.y * (float)ph[5],
                               fb.z * (float)ph[6], fb.w * (float)ph[7]};
                half8 h;
#pragma unroll
                for (int j = 0; j < 8; ++j) h[j] = (_Float16)xs[j];
                A[sl] = h;
            }
#pragma unroll
            for (int sl = 0; sl < 2; ++sl) {
                int k0 = sl * 32 + k0q;
                float r[8] = {0, 0, 0, 0, 0, 0, 0, 0};
#pragma unroll
                for (int j = 0; j < 5; ++j) {
                    const float* fr = feat + (ij[j] << 6);
                    floatx4 fa = *(const floatx4*)(fr + k0);
                    floatx4 fb = *(const floatx4*)(fr + k0 + 4);
                    half8 pv = *(const half8*)(sPh + bj[j] * PPADH + k0);
                    r[0] = fmaf(fa.x, (float)pv[0], r[0]);
                    r[1] = fmaf(fa.y, (float)pv[1], r[1]);
                    r[2] = fmaf(fa.z, (float)pv[2], r[2]);
                    r[3] = fmaf(fa.w, (float)pv[3], r[3]);
                    r[4] = fmaf(fb.x, (float)pv[4], r[4]);
                    r[5] = fmaf(fb.y, (float)pv[5], r[5]);
                    r[6] = fmaf(fb.z, (float)pv[6], r[6]);
                    r[7] = fmaf(fb.w, (float)pv[7], r[7]);
                }
                half8 h;
#pragma unroll
                for (int j = 0; j < 8; ++j) h[j] = (_Float16)(r[j] * 0.2f);
                A[2 + sl] = h;
            }
        }

        // ---- MFMA: 4 k-slabs x 4 n-tiles, single f16 product --------------
        floatx4 acc[4] = {{0, 0, 0, 0}, {0, 0, 0, 0}, {0, 0, 0, 0}, {0, 0, 0, 0}};
#pragma unroll
        for (int sl = 0; sl < 4; ++sl) {
#pragma unroll
            for (int nt = 0; nt < 4; ++nt) {
                half8 b = sWB[((sl << 2) + nt) * 64 + lane];
                acc[nt] = __builtin_amdgcn_mfma_f32_16x16x32_f16(
                    A[sl], b, acc[nt], 0, 0, 0);
            }
        }

        // ---- merged epilogue: dst-sorted => equal-dst runs among the 16 ---
        const int q4 = quad << 2;
        const int dm0 = __shfl(d, q4 + 0), dm1 = __shfl(d, q4 + 1);
        const int dm2 = __shfl(d, q4 + 2), dm3 = __shfl(d, q4 + 3);
        const float sc0 = __shfl(dsc, q4 + 0), sc1 = __shfl(dsc, q4 + 1);
        const float sc2 = __shfl(dsc, q4 + 2), sc3 = __shfl(dsc, q4 + 3);
        const int dmn = __shfl(d, (q4 + 4) & 15);
        const int dmp = __shfl(d, (q4 - 1) & 15);
        const bool eq0 = dm0 == dm1, eq1 = dm1 == dm2, eq2 = dm2 == dm3;
        const bool eq3 = (quad < 3) && (dm3 == dmn);
        const bool lnk = (quad > 0) && (dmp == dm0);
        const bool alls = eq0 && eq1 && eq2;
        const bool gate = alls && lnk;

        float w0[4], w1[4], w2[4], w3[4], Ci[4];
#pragma unroll
        for (int nt = 0; nt < 4; ++nt) {
            w0[nt] = (acc[nt][0] + bias4[nt]) * sc0;
            w1[nt] = (acc[nt][1] + bias4[nt]) * sc1;
            w2[nt] = (acc[nt][2] + bias4[nt]) * sc2;
            w3[nt] = (acc[nt][3] + bias4[nt]) * sc3;
            if (eq0) w1[nt] += w0[nt];
            if (eq1) w2[nt] += w1[nt];
            if (eq2) w3[nt] += w2[nt];
            float T = w3[nt];
#pragma unroll
            for (int k = 0; k < 3; ++k) {
                float Tp = __shfl(T, (lane - 16) & 63);
                T = w3[nt] + (gate ? Tp : 0.0f);
            }
            float c = __shfl(T, (lane - 16) & 63);
            Ci[nt] = lnk ? c : 0.0f;
        }

        if (!eq0) {
            float* ap = rst + (dm0 << 6) + m16;
            float v0 = w0[0] + Ci[0], v1 = w0[1] + Ci[1];
            float v2 = w0[2] + Ci[2], v3 = w0[3] + Ci[3];
            asm volatile("global_atomic_add_f32 %0, %1, off nt" :: "v"(ap), "v"(v0));
            asm volatile("global_atomic_add_f32 %0, %1, off offset:64 nt" :: "v"(ap), "v"(v1));
            asm volatile("global_atomic_add_f32 %0, %1, off offset:128 nt" :: "v"(ap), "v"(v2));
            asm volatile("global_atomic_add_f32 %0, %1, off offset:192 nt" :: "v"(ap), "v"(v3));
        }
        if (!eq1) {
            float* ap = rst + (dm1 << 6) + m16;
            float h0 = eq0 ? Ci[0] : 0.0f, h1 = eq0 ? Ci[1] : 0.0f;
            float h2 = eq0 ? Ci[2] : 0.0f, h3 = eq0 ? Ci[3] : 0.0f;
            float v0 = w1[0] + h0, v1 = w1[1] + h1;
            float v2 = w1[2] + h2, v3 = w1[3] + h3;
            asm volatile("global_atomic_add_f32 %0, %1, off nt" :: "v"(ap), "v"(v0));
            asm volatile("global_atomic_add_f32 %0, %1, off offset:64 nt" :: "v"(ap), "v"(v1));
            asm volatile("global_atomic_add_f32 %0, %1, off offset:128 nt" :: "v"(ap), "v"(v2));
            asm volatile("global_atomic_add_f32 %0, %1, off offset:192 nt" :: "v"(ap), "v"(v3));
        }
        if (!eq2) {
            const bool hr = eq0 && eq1;
            float* ap = rst + (dm2 << 6) + m16;
            float v0 = w2[0] + (hr ? Ci[0] : 0.0f), v1 = w2[1] + (hr ? Ci[1] : 0.0f);
            float v2 = w2[2] + (hr ? Ci[2] : 0.0f), v3 = w2[3] + (hr ? Ci[3] : 0.0f);
            asm volatile("global_atomic_add_f32 %0, %1, off nt" :: "v"(ap), "v"(v0));
            asm volatile("global_atomic_add_f32 %0, %1, off offset:64 nt" :: "v"(ap), "v"(v1));
            asm volatile("global_atomic_add_f32 %0, %1, off offset:128 nt" :: "v"(ap), "v"(v2));
            asm volatile("global_atomic_add_f32 %0, %1, off offset:192 nt" :: "v"(ap), "v"(v3));
        }
        if (!eq3) {
            float* ap = rst + (dm3 << 6) + m16;
            float v0 = w3[0] + (alls ? Ci[0] : 0.0f), v1 = w3[1] + (alls ? Ci[1] : 0.0f);
            float v2 = w3[2] + (alls ? Ci[2] : 0.0f), v3 = w3[3] + (alls ? Ci[3] : 0.0f);
            asm volatile("global_atomic_add_f32 %0, %1, off nt" :: "v"(ap), "v"(v0));
            asm volatile("global_atomic_add_f32 %0, %1, off offset:64 nt" :: "v"(ap), "v"(v1));
            asm volatile("global_atomic_add_f32 %0, %1, off offset:128 nt" :: "v"(ap), "v"(v2));
            asm volatile("global_atomic_add_f32 %0, %1, off offset:192 nt" :: "v"(ap), "v"(v3));
        }
    }
}

extern "C" void kernel_launch(void* const* d_in, const int* in_sizes, int n_in,
                              void* d_out, int out_size, void* d_ws,
                              size_t ws_size, hipStream_t stream) {
    const float* feat  = (const float*)d_in[0];
    const float* loc   = (const float*)d_in[1];
    const float* embed = (const float*)d_in[2];
    const float* G_w   = (const float*)d_in[3];
    const float* agg_w = (const float*)d_in[4];
    const float* agg_b = (const float*)d_in[5];
    const float* bnds  = (const float*)d_in[6];
    const int* src   = (const int*)d_in[7];
    const int* dst   = (const int*)d_in[8];
    const int* inter = (const int*)d_in[9];

    const int N = in_sizes[0] / DFEAT;
    const int E = in_sizes[7];
    const int ngroups = (E + 15) >> 4;
    const int paddedE = ngroups << 4;
    const int NB = (N + SCHUNK - 1) / SCHUNK;

    float* rst = (float*)d_out;
    char* wsb = (char*)d_ws;

    auto al16 = [](size_t x) { return (x + 15) & ~(size_t)15; };
    size_t off_degs = 0;
    size_t off_p = al16(off_degs + 2 * (size_t)N * 4);
    size_t off_scale = al16(off_p + 65 * DFEAT * 2);
    size_t off_q = al16(off_scale + (size_t)N * 4);
    size_t off_bin = al16(off_q + (size_t)N * DFEAT);
    size_t off_pack = al16(off_bin + (size_t)N * 4);
    size_t off_bsum = off_pack + 32 * (size_t)paddedE;
    size_t need_all = off_bsum + (size_t)NB * 4;

    float* degs = (float*)(wsb + off_degs);
    _Float16* Ph = (_Float16*)(wsb + off_p);
    float* scaleQ = (float*)(wsb + off_scale);
    signed char* featQ =
        (ws_size >= off_bin) ? (signed char*)(wsb + off_q) : nullptr;
    int* binptr = nullptr;
    int* pack = nullptr;
    int* bsum = nullptr;
    if (ws_size >= need_all && N < (1 << 20) && NB <= 1024 && featQ) {
        binptr = (int*)(wsb + off_bin);
        pack = (int*)(wsb + off_pack);
        bsum = (int*)(wsb + off_bsum);
    }

    const int nRst = N * DFEAT;
    const int nDeg = 2 * N;

    k_prep<<<(nRst + 255) / 256, 256, 0, stream>>>(
        embed, G_w, Ph, rst, degs, feat, featQ, scaleQ, nRst, nDeg);
    k_deg<<<(E + 255) / 256, 256, 0, stream>>>(src, dst, degs, N, E);
    if (pack) {
        k_scanA<<<NB, 256, 0, stream>>>(degs, bsum, N);
        k_scanC<<<NB, 256, 0, stream>>>(degs, bsum, binptr, N, NB);
        k_scatter<<<(paddedE + 255) / 256, 256, 0, stream>>>(
            src, dst, inter, loc, degs, bnds, binptr, pack, N, E, paddedE);
    }
    // LDS 25744 B/block -> 6 blocks/CU (24 waves); 1536 blocks resident.
    // Static contiguous chunks (R17-proven; dynamic pop poisoned by R20).
    k_edge<<<1536, 256, 0, stream>>>(feat, featQ, scaleQ, loc, agg_w, agg_b,
                                     bnds, src, dst, inter, pack, Ph, degs,
                                     rst, N, E);
}